// Round 6
// baseline (399.292 us; speedup 1.0000x reference)
//
#include <hip/hip_runtime.h>
#include <hip/hip_bf16.h>

// (B,N,T,F) = (16,512,24,64). FP32 in/out.
#define BB 16
#define NN 512
#define TT 24
#define FF 64
#define OUT_OFF ((size_t)BB*NN*TT*FF)   // 12582912 floats (of | uf concatenated)

#define AIS 136      // Aj row stride, shorts (272B = 17*16B)
#define XTS 72       // XT/UT/O/W row stride (144B = 9*16B)
#define XTSZ 4672    // per-matrix region (64*72 + swizzle slack)

#define AE  12582912               // elements per full tensor (B*N*T*F)
#define SQRT_L2E 1.2011224087f     // sqrt(log2(e))

// ws layout (bytes):
//   xH:0  xL:2*AE  xT:4*AE  uT:6*AE   (each AE shorts = 2*AE bytes)
//   eH:8*AE  (65536)  eL:+65536  wH:+65536 (8192)
//   h2x:+8192 (786432 f32)  ne2:+786432 (2048)  mArr:+2048 (786432)
#define WS_EH   ((size_t)8*AE)
#define WS_EL   (WS_EH + 65536)
#define WS_WH   (WS_EL + 65536)
#define WS_H2X  (WS_WH + 8192)
#define WS_NE2  (WS_H2X + 786432)
#define WS_M    (WS_NE2 + 2048)
#define WS_NEED (WS_M + 786432)    // 102377472

typedef __attribute__((ext_vector_type(8))) short v8s;
typedef __attribute__((ext_vector_type(4))) float v4f;

union U16x8 { uint4 v; unsigned short s[8]; };

__device__ inline v4f mfma16(v8s a, v8s b, v4f c) {
    return __builtin_amdgcn_mfma_f32_16x16x32_bf16(a, b, c, 0, 0, 0);
}
__device__ inline unsigned short f2bf(float x) {
    union { __hip_bfloat16 h; unsigned short u; } cv; cv.h = __float2bfloat16(x); return cv.u;
}
__device__ inline float bf2f(unsigned short u) {
    union { float f; unsigned int i; } cv; cv.i = ((unsigned int)u) << 16; return cv.f;
}
__device__ inline void cvt8u(const float* f, U16x8& H, U16x8& L) {
    #pragma unroll
    for (int k = 0; k < 8; ++k) {
        unsigned short h = f2bf(f[k]);
        H.s[k] = h;
        L.s[k] = f2bf(f[k] - bf2f(h));
    }
}

// ================= prep 1: convert + transpose ori/unc =================
// grid 1536 = (b*T+t)*4 + nc; 256 threads. Handles 128 n-rows.
__global__ __launch_bounds__(256)
void prep_x(const float* __restrict__ ori, const float* __restrict__ unc,
            unsigned short* __restrict__ xH, unsigned short* __restrict__ xL,
            unsigned short* __restrict__ xT, unsigned short* __restrict__ uT,
            float* __restrict__ h2x)
{
    __shared__ unsigned short TX[64*128];   // [f][n_local] unscaled hi of x
    __shared__ unsigned short TU[64*128];
    const int tid = threadIdx.x;
    const int bt = blockIdx.x >> 2, nc = blockIdx.x & 3;
    const int b = bt / TT, t = bt % TT, n0 = nc * 128;
    const int isU = tid >= 128;
    const int lr  = (tid & 127) >> 2;       // 0..31
    const int f0  = (tid & 3) * 16;

    #pragma unroll
    for (int pass = 0; pass < 4; ++pass) {
        int r = pass * 32 + lr;             // 0..127
        int n = n0 + r;
        size_t g = ((size_t)((b*NN + n)*TT + t))*FF + f0;
        float v[16];
        const float* src = isU ? unc : ori;
        #pragma unroll
        for (int h = 0; h < 4; ++h) *(float4*)&v[4*h] = *(const float4*)(src + g + 4*h);
        if (!isU) {
            U16x8 H[2], L[2];
            float s2 = 0.0f;
            #pragma unroll
            for (int k = 0; k < 16; ++k) {
                float xs = v[k] * SQRT_L2E;
                unsigned short h = f2bf(xs);
                H[k>>3].s[k&7] = h;
                L[k>>3].s[k&7] = f2bf(xs - bf2f(h));
                s2 += xs * xs;
                TX[(f0 + k)*128 + r] = f2bf(v[k]);   // unscaled hi for PV
            }
            *(uint4*)(xH + g)     = H[0].v; *(uint4*)(xH + g + 8) = H[1].v;
            *(uint4*)(xL + g)     = L[0].v; *(uint4*)(xL + g + 8) = L[1].v;
            s2 += __shfl_xor(s2, 1);
            s2 += __shfl_xor(s2, 2);
            if ((tid & 3) == 0) h2x[bt*NN + n] = s2;
        } else {
            #pragma unroll
            for (int k = 0; k < 16; ++k) TU[(f0 + k)*128 + r] = f2bf(v[k]);
        }
    }
    __syncthreads();
    // write transposed tiles: xT[bt][f][n]
    const int f = tid >> 2, c = (tid & 3) * 32;
    size_t o = ((size_t)(bt*FF + f))*NN + n0 + c;
    #pragma unroll
    for (int m = 0; m < 4; ++m) {
        *(uint4*)(xT + o + 8*m) = *(const uint4*)&TX[f*128 + c + 8*m];
        *(uint4*)(uT + o + 8*m) = *(const uint4*)&TU[f*128 + c + 8*m];
    }
}

// ================= prep E: emb + W1 =================
__global__ __launch_bounds__(256)
void prep_e(const float* __restrict__ emb, const float* __restrict__ W1,
            unsigned short* __restrict__ eH, unsigned short* __restrict__ eL,
            float* __restrict__ ne2, unsigned short* __restrict__ wH)
{
    const int tid = threadIdx.x;
    const int f0 = (tid & 3) * 16, r0 = tid >> 2;
    #pragma unroll
    for (int pass = 0; pass < 8; ++pass) {
        int r = pass*64 + r0;
        size_t g = (size_t)r*FF + f0;
        float v[16];
        #pragma unroll
        for (int h = 0; h < 4; ++h) *(float4*)&v[4*h] = *(const float4*)(emb + g + 4*h);
        U16x8 H[2], L[2];
        float s2 = 0.0f;
        #pragma unroll
        for (int k = 0; k < 16; ++k) {
            float xs = v[k] * SQRT_L2E;
            unsigned short h = f2bf(xs);
            H[k>>3].s[k&7] = h;
            L[k>>3].s[k&7] = f2bf(xs - bf2f(h));
            s2 += xs * xs;
        }
        *(uint4*)(eH + g)     = H[0].v; *(uint4*)(eH + g + 8) = H[1].v;
        *(uint4*)(eL + g)     = L[0].v; *(uint4*)(eL + g + 8) = L[1].v;
        s2 += __shfl_xor(s2, 1);
        s2 += __shfl_xor(s2, 2);
        if ((tid & 3) == 0) ne2[r] = s2;
    }
    // W1 (unscaled hi)
    {
        size_t g = (size_t)r0*FF + f0;
        float v[16];
        #pragma unroll
        for (int h = 0; h < 4; ++h) *(float4*)&v[4*h] = *(const float4*)(W1 + g + 4*h);
        U16x8 H[2];
        #pragma unroll
        for (int k = 0; k < 16; ++k) H[k>>3].s[k&7] = f2bf(v[k]);
        *(uint4*)(wH + g) = H[0].v; *(uint4*)(wH + g + 8) = H[1].v;
    }
}

// ================= prep 2: Cauchy-Schwarz row bounds =================
__global__ __launch_bounds__(256)
void prep_m(const float* __restrict__ h2x, const float* __restrict__ ne2,
            float* __restrict__ mArr)
{
    __shared__ float red[4];
    __shared__ float h2s[512];
    const int tid = threadIdx.x, bt = blockIdx.x;
    float mx = 0.0f;
    #pragma unroll
    for (int k = 0; k < 2; ++k) {
        int n = tid + 256*k;
        float h2 = h2x[bt*NN + n] + ne2[n];
        h2s[n] = h2;
        mx = fmaxf(mx, h2);
    }
    #pragma unroll
    for (int d = 1; d < 64; d <<= 1) mx = fmaxf(mx, __shfl_xor(mx, d));
    if ((tid & 63) == 0) red[tid >> 6] = mx;
    __syncthreads();
    float M = fmaxf(fmaxf(red[0], red[1]), fmaxf(red[2], red[3]));
    #pragma unroll
    for (int k = 0; k < 2; ++k) {
        int n = tid + 256*k;
        mArr[bt*NN + n] = sqrtf(h2s[n] * M) + 0.5f;
    }
}

// ================= main kernel (lean staging, fixed-m softmax) =================
__global__ __launch_bounds__(256, 3)
void spag_main(const unsigned short* __restrict__ xH, const unsigned short* __restrict__ xL,
               const unsigned short* __restrict__ xT, const unsigned short* __restrict__ uT,
               const unsigned short* __restrict__ eH, const unsigned short* __restrict__ eL,
               const unsigned short* __restrict__ wH, const float* __restrict__ mArr,
               float* __restrict__ out)
{
    __shared__ __align__(16) unsigned short SH[2*64*AIS + 2*XTSZ];   // 53504 B
    unsigned short* AjH = SH;
    unsigned short* AjL = SH + 64*AIS;
    unsigned short* XT  = SH + 2*64*AIS;
    unsigned short* UT  = XT + XTSZ;

    const int tid  = threadIdx.x;
    const int bt   = blockIdx.x >> 3;
    const int it   = blockIdx.x & 7;
    const int b    = bt / TT, t = bt % TT;
    const int i0   = it * 64;

    const int lane = tid & 63;
    const int w    = tid >> 6;
    const int q    = lane >> 4;
    const int lc   = lane & 15;

    const int sr = tid >> 2, fc = (tid & 3) * 16;   // row-staging map
    const int tf = tid >> 2, jc = (tid & 3) * 16;   // transposed-staging map

    // ---- prologue: stage Ai (bf16 direct) ----
    {
        size_t gx = ((size_t)((b*NN + i0 + sr)*TT + t))*FF + fc;
        size_t ge = (size_t)(i0 + sr)*FF + fc;
        *(uint4*)&AjH[sr*AIS + fc]          = *(const uint4*)(xH + gx);
        *(uint4*)&AjH[sr*AIS + fc + 8]      = *(const uint4*)(xH + gx + 8);
        *(uint4*)&AjH[sr*AIS + 64 + fc]     = *(const uint4*)(eH + ge);
        *(uint4*)&AjH[sr*AIS + 64 + fc + 8] = *(const uint4*)(eH + ge + 8);
        *(uint4*)&AjL[sr*AIS + fc]          = *(const uint4*)(xL + gx);
        *(uint4*)&AjL[sr*AIS + fc + 8]      = *(const uint4*)(xL + gx + 8);
        *(uint4*)&AjL[sr*AIS + 64 + fc]     = *(const uint4*)(eL + ge);
        *(uint4*)&AjL[sr*AIS + 64 + fc + 8] = *(const uint4*)(eL + ge + 8);
    }
    __syncthreads();

    v8s bH[4], bL[4];
    #pragma unroll
    for (int kk = 0; kk < 4; ++kk) {
        bH[kk] = *(const v8s*)&AjH[(w*16+lc)*AIS + kk*32 + q*8];
        bL[kk] = *(const v8s*)&AjL[(w*16+lc)*AIS + kk*32 + q*8];
    }
    const float m_own = mArr[bt*NN + i0 + w*16 + lc];   // CS bound for row i (log2 space)

    v4f accX[4], accU[4];
    #pragma unroll
    for (int ft = 0; ft < 4; ++ft) { accX[ft] = (v4f)(0.0f); accU[ft] = (v4f)(0.0f); }
    float rs = 0.0f;

    for (int jt = 0; jt < 8; ++jt) {
        const int j0 = jt * 64;
        __syncthreads();

        // ---- staging: pure copies ----
        {
            size_t gx = ((size_t)((b*NN + j0 + sr)*TT + t))*FF + fc;
            size_t ge = (size_t)(j0 + sr)*FF + fc;
            *(uint4*)&AjH[sr*AIS + fc]          = *(const uint4*)(xH + gx);
            *(uint4*)&AjH[sr*AIS + fc + 8]      = *(const uint4*)(xH + gx + 8);
            *(uint4*)&AjH[sr*AIS + 64 + fc]     = *(const uint4*)(eH + ge);
            *(uint4*)&AjH[sr*AIS + 64 + fc + 8] = *(const uint4*)(eH + ge + 8);
            *(uint4*)&AjL[sr*AIS + fc]          = *(const uint4*)(xL + gx);
            *(uint4*)&AjL[sr*AIS + fc + 8]      = *(const uint4*)(xL + gx + 8);
            *(uint4*)&AjL[sr*AIS + 64 + fc]     = *(const uint4*)(eL + ge);
            *(uint4*)&AjL[sr*AIS + 64 + fc + 8] = *(const uint4*)(eL + ge + 8);
            size_t gt = ((size_t)(bt*FF + tf))*NN + j0 + jc;
            int off = tf*XTS + (tf>>4)*16 + jc;
            *(uint4*)&XT[off]     = *(const uint4*)(xT + gt);
            *(uint4*)&XT[off + 8] = *(const uint4*)(xT + gt + 8);
            *(uint4*)&UT[off]     = *(const uint4*)(uT + gt);
            *(uint4*)&UT[off + 8] = *(const uint4*)(uT + gt + 8);
        }
        __syncthreads();

        // ---- scores (S^T, hi/lo split, 48 MFMA) ----
        v4f C[4] = {(v4f)(0.0f),(v4f)(0.0f),(v4f)(0.0f),(v4f)(0.0f)};
        #pragma unroll
        for (int kk = 0; kk < 4; ++kk) {
            #pragma unroll
            for (int st = 0; st < 4; ++st) {
                v8s aH = *(const v8s*)&AjH[(st*16+lc)*AIS + kk*32 + q*8];
                v8s aL = *(const v8s*)&AjL[(st*16+lc)*AIS + kk*32 + q*8];
                C[st] = mfma16(aH, bH[kk], C[st]);
                C[st] = mfma16(aH, bL[kk], C[st]);
                C[st] = mfma16(aL, bH[kk], C[st]);
            }
        }

        // ---- p = 2^(relu(s~) - m~)  (fixed bound: no online rescale) ----
        #pragma unroll
        for (int st = 0; st < 4; ++st) {
            #pragma unroll
            for (int r = 0; r < 4; ++r)
                C[st][r] = exp2f(fmaxf(C[st][r], 0.0f) - m_own);
        }

        // ---- repack C-layout -> A-layout (in-wave shfl), rowsum ----
        v8s P[2];
        #pragma unroll
        for (int kk = 0; kk < 2; ++kk) {
            union { v8s v; unsigned short s[8]; } pf;
            #pragma unroll
            for (int jj = 0; jj < 8; ++jj) {
                int src = ((q & 1)*2 + (jj >> 2))*16 + lc;
                float v0 = __shfl(C[2*kk + 0][jj & 3], src);
                float v1 = __shfl(C[2*kk + 1][jj & 3], src);
                float pv = (q >> 1) ? v1 : v0;
                unsigned short pb = f2bf(pv);
                pf.s[jj] = pb;
                rs += bf2f(pb);
            }
            P[kk] = pf.v;
        }

        // ---- PV (16 MFMA) ----
        #pragma unroll
        for (int ft = 0; ft < 4; ++ft) {
            #pragma unroll
            for (int kk = 0; kk < 2; ++kk) {
                v8s bx = *(const v8s*)&XT[(ft*16+lc)*XTS + ft*16 + kk*32 + q*8];
                v8s bu = *(const v8s*)&UT[(ft*16+lc)*XTS + ft*16 + kk*32 + q*8];
                accX[ft] = mfma16(P[kk], bx, accX[ft]);
                accU[ft] = mfma16(P[kk], bu, accU[ft]);
            }
        }
    }

    // ---- epilogue ----
    __syncthreads();
    rs += __shfl_xor(rs, 16);
    rs += __shfl_xor(rs, 32);
    float inv = 1.0f / rs;
    float invr[4];
    #pragma unroll
    for (int r = 0; r < 4; ++r) invr[r] = __shfl(inv, q*4 + r);

    unsigned short* Ox = XT;
    unsigned short* Ou = UT;
    #pragma unroll
    for (int ft = 0; ft < 4; ++ft) {
        #pragma unroll
        for (int r = 0; r < 4; ++r) {
            int row = w*16 + q*4 + r;
            Ox[row*XTS + ft*16 + lc] = f2bf(accX[ft][r] * invr[r]);
            Ou[row*XTS + ft*16 + lc] = f2bf(accU[ft][r] * invr[r]);
        }
    }
    {
        *(uint4*)&AjH[sr*XTS + fc]     = *(const uint4*)(wH + sr*FF + fc);
        *(uint4*)&AjH[sr*XTS + fc + 8] = *(const uint4*)(wH + sr*FF + fc + 8);
    }
    __syncthreads();

    #pragma unroll
    for (int ot = 0; ot < 4; ++ot) {
        v4f ax = (v4f)(0.0f), au = (v4f)(0.0f);
        #pragma unroll
        for (int kk = 0; kk < 2; ++kk) {
            v8s aox = *(const v8s*)&Ox[(w*16+lc)*XTS + kk*32 + q*8];
            v8s aou = *(const v8s*)&Ou[(w*16+lc)*XTS + kk*32 + q*8];
            v8s bw  = *(const v8s*)&AjH[(ot*16+lc)*XTS + kk*32 + q*8];
            ax = mfma16(aox, bw, ax);
            au = mfma16(aou, bw, au);
        }
        #pragma unroll
        for (int r = 0; r < 4; ++r) {
            int i = i0 + w*16 + q*4 + r;
            int o = ot*16 + lc;
            size_t idx = ((size_t)((b*NN + i)*TT + t))*FF + o;
            out[idx]           = fmaxf(ax[r], 0.0f);
            out[OUT_OFF + idx] = fmaxf(au[r], 0.0f);
        }
    }
}

// ================= fallback: round-5 kernel (ws too small) =================
__global__ __launch_bounds__(256, 3)
void spag_fb(const float* __restrict__ ori, const float* __restrict__ unc,
             const float* __restrict__ emb, const float* __restrict__ W1,
             float* __restrict__ out)
{
    __shared__ __align__(16) unsigned short SH[2*64*AIS + 2*XTSZ];
    unsigned short* AjH = SH;
    unsigned short* AjL = SH + 64*AIS;
    unsigned short* XT  = SH + 2*64*AIS;
    unsigned short* UT  = XT + XTSZ;

    const int tid  = threadIdx.x;
    const int bt   = blockIdx.x >> 3;
    const int it   = blockIdx.x & 7;
    const int b    = bt / TT, t = bt % TT;
    const int i0   = it * 64;
    const int lane = tid & 63;
    const int w    = tid >> 6;
    const int q    = lane >> 4;
    const int lc   = lane & 15;

    {
        const int sr = tid >> 2, fc = (tid & 3) * 16;
        const float* xb = ori + ((size_t)((b*NN + i0 + sr)*TT + t))*FF + fc;
        const float* eb = emb + (size_t)(i0 + sr)*FF + fc;
        float tf[8]; U16x8 H, L;
        #pragma unroll
        for (int h = 0; h < 2; ++h) {
            *(float4*)&tf[0] = ((const float4*)xb)[2*h];
            *(float4*)&tf[4] = ((const float4*)xb)[2*h+1];
            cvt8u(tf, H, L);
            *(uint4*)&AjH[sr*AIS + fc + h*8] = H.v;
            *(uint4*)&AjL[sr*AIS + fc + h*8] = L.v;
            *(float4*)&tf[0] = ((const float4*)eb)[2*h];
            *(float4*)&tf[4] = ((const float4*)eb)[2*h+1];
            cvt8u(tf, H, L);
            *(uint4*)&AjH[sr*AIS + 64 + fc + h*8] = H.v;
            *(uint4*)&AjL[sr*AIS + 64 + fc + h*8] = L.v;
        }
    }
    __syncthreads();

    v8s bH[4], bL[4];
    #pragma unroll
    for (int kk = 0; kk < 4; ++kk) {
        bH[kk] = *(const v8s*)&AjH[(w*16+lc)*AIS + kk*32 + q*8];
        bL[kk] = *(const v8s*)&AjL[(w*16+lc)*AIS + kk*32 + q*8];
    }

    v4f accX[4], accU[4];
    #pragma unroll
    for (int ft = 0; ft < 4; ++ft) { accX[ft] = (v4f)(0.0f); accU[ft] = (v4f)(0.0f); }
    float rs = 0.0f, m_run = 0.0f;

    for (int jt = 0; jt < 8; ++jt) {
        const int j0 = jt * 64;
        __syncthreads();
        {
            const int pj = tid >> 3;
            const int f0 = (tid & 7) * 8;
            const int j  = 2 * pj;
            const size_t r0 = ((size_t)((b*NN + j0 + j)*TT + t))*FF + f0;
            const size_t r1 = r0 + (size_t)TT*FF;
            float t0[8], t1[8]; U16x8 H0, L0, H1, L1;
            *(float4*)&t0[0] = *(const float4*)(ori + r0);
            *(float4*)&t0[4] = *(const float4*)(ori + r0 + 4);
            *(float4*)&t1[0] = *(const float4*)(ori + r1);
            *(float4*)&t1[4] = *(const float4*)(ori + r1 + 4);
            cvt8u(t0, H0, L0); cvt8u(t1, H1, L1);
            *(uint4*)&AjH[ j   *AIS + f0] = H0.v;
            *(uint4*)&AjH[(j+1)*AIS + f0] = H1.v;
            *(uint4*)&AjL[ j   *AIS + f0] = L0.v;
            *(uint4*)&AjL[(j+1)*AIS + f0] = L1.v;
            #pragma unroll
            for (int k = 0; k < 8; ++k) {
                int f = f0 + k;
                int off = f*XTS + (f>>4)*16 + j;
                *(unsigned int*)&XT[off] =
                    (unsigned int)H0.s[k] | ((unsigned int)H1.s[k] << 16);
            }
            const float* e0 = emb + (size_t)(j0 + j)*FF + f0;
            *(float4*)&t0[0] = *(const float4*)(e0);
            *(float4*)&t0[4] = *(const float4*)(e0 + 4);
            *(float4*)&t1[0] = *(const float4*)(e0 + FF);
            *(float4*)&t1[4] = *(const float4*)(e0 + FF + 4);
            cvt8u(t0, H0, L0); cvt8u(t1, H1, L1);
            *(uint4*)&AjH[ j   *AIS + 64 + f0] = H0.v;
            *(uint4*)&AjH[(j+1)*AIS + 64 + f0] = H1.v;
            *(uint4*)&AjL[ j   *AIS + 64 + f0] = L0.v;
            *(uint4*)&AjL[(j+1)*AIS + 64 + f0] = L1.v;
            *(float4*)&t0[0] = *(const float4*)(unc + r0);
            *(float4*)&t0[4] = *(const float4*)(unc + r0 + 4);
            *(float4*)&t1[0] = *(const float4*)(unc + r1);
            *(float4*)&t1[4] = *(const float4*)(unc + r1 + 4);
            #pragma unroll
            for (int k = 0; k < 8; ++k) {
                int f = f0 + k;
                int off = f*XTS + (f>>4)*16 + j;
                *(unsigned int*)&UT[off] =
                    (unsigned int)f2bf(t0[k]) | ((unsigned int)f2bf(t1[k]) << 16);
            }
        }
        __syncthreads();

        v4f C[4] = {(v4f)(0.0f),(v4f)(0.0f),(v4f)(0.0f),(v4f)(0.0f)};
        #pragma unroll
        for (int kk = 0; kk < 4; ++kk) {
            #pragma unroll
            for (int st = 0; st < 4; ++st) {
                v8s aH = *(const v8s*)&AjH[(st*16+lc)*AIS + kk*32 + q*8];
                v8s aL = *(const v8s*)&AjL[(st*16+lc)*AIS + kk*32 + q*8];
                C[st] = mfma16(aH, bH[kk], C[st]);
                C[st] = mfma16(aH, bL[kk], C[st]);
                C[st] = mfma16(aL, bH[kk], C[st]);
            }
        }
        float mt = 0.0f;
        #pragma unroll
        for (int st = 0; st < 4; ++st) {
            #pragma unroll
            for (int r = 0; r < 4; ++r) {
                float s = fmaxf(C[st][r], 0.0f);
                C[st][r] = s;
                mt = fmaxf(mt, s);
            }
        }
        mt = fmaxf(mt, __shfl_xor(mt, 16));
        mt = fmaxf(mt, __shfl_xor(mt, 32));
        float m_new = fmaxf(m_run, mt);
        float alpha = __expf(m_run - m_new);
        rs *= alpha;
        m_run = m_new;
        float alphar[4];
        #pragma unroll
        for (int r = 0; r < 4; ++r) alphar[r] = __shfl(alpha, q*4 + r);
        #pragma unroll
        for (int ft = 0; ft < 4; ++ft) {
            #pragma unroll
            for (int r = 0; r < 4; ++r) { accX[ft][r] *= alphar[r]; accU[ft][r] *= alphar[r]; }
        }
        #pragma unroll
        for (int st = 0; st < 4; ++st) {
            #pragma unroll
            for (int r = 0; r < 4; ++r) C[st][r] = __expf(C[st][r] - m_new);
        }
        v8s P[2];
        #pragma unroll
        for (int kk = 0; kk < 2; ++kk) {
            union { v8s v; unsigned short s[8]; } pf;
            #pragma unroll
            for (int jj = 0; jj < 8; ++jj) {
                int src = ((q & 1)*2 + (jj >> 2))*16 + lc;
                float v0 = __shfl(C[2*kk + 0][jj & 3], src);
                float v1 = __shfl(C[2*kk + 1][jj & 3], src);
                float pv = (q >> 1) ? v1 : v0;
                unsigned short pb = f2bf(pv);
                pf.s[jj] = pb;
                rs += bf2f(pb);
            }
            P[kk] = pf.v;
        }
        #pragma unroll
        for (int ft = 0; ft < 4; ++ft) {
            #pragma unroll
            for (int kk = 0; kk < 2; ++kk) {
                v8s bx = *(const v8s*)&XT[(ft*16+lc)*XTS + ft*16 + kk*32 + q*8];
                v8s bu = *(const v8s*)&UT[(ft*16+lc)*XTS + ft*16 + kk*32 + q*8];
                accX[ft] = mfma16(P[kk], bx, accX[ft]);
                accU[ft] = mfma16(P[kk], bu, accU[ft]);
            }
        }
    }
    __syncthreads();
    rs += __shfl_xor(rs, 16);
    rs += __shfl_xor(rs, 32);
    float inv = 1.0f / rs;
    float invr[4];
    #pragma unroll
    for (int r = 0; r < 4; ++r) invr[r] = __shfl(inv, q*4 + r);
    unsigned short* Ox = XT;
    unsigned short* Ou = UT;
    #pragma unroll
    for (int ft = 0; ft < 4; ++ft) {
        #pragma unroll
        for (int r = 0; r < 4; ++r) {
            int row = w*16 + q*4 + r;
            Ox[row*XTS + ft*16 + lc] = f2bf(accX[ft][r] * invr[r]);
            Ou[row*XTS + ft*16 + lc] = f2bf(accU[ft][r] * invr[r]);
        }
    }
    {
        const int sr = tid >> 2, fc = (tid & 3) * 16;
        const float* wb = W1 + sr*FF + fc;
        float tf[8]; U16x8 H, L;
        #pragma unroll
        for (int h = 0; h < 2; ++h) {
            *(float4*)&tf[0] = ((const float4*)wb)[2*h];
            *(float4*)&tf[4] = ((const float4*)wb)[2*h+1];
            cvt8u(tf, H, L);
            *(uint4*)&AjH[sr*XTS + fc + h*8] = H.v;
        }
    }
    __syncthreads();
    #pragma unroll
    for (int ot = 0; ot < 4; ++ot) {
        v4f ax = (v4f)(0.0f), au = (v4f)(0.0f);
        #pragma unroll
        for (int kk = 0; kk < 2; ++kk) {
            v8s aox = *(const v8s*)&Ox[(w*16+lc)*XTS + kk*32 + q*8];
            v8s aou = *(const v8s*)&Ou[(w*16+lc)*XTS + kk*32 + q*8];
            v8s bw  = *(const v8s*)&AjH[(ot*16+lc)*XTS + kk*32 + q*8];
            ax = mfma16(aox, bw, ax);
            au = mfma16(aou, bw, au);
        }
        #pragma unroll
        for (int r = 0; r < 4; ++r) {
            int i = i0 + w*16 + q*4 + r;
            int o = ot*16 + lc;
            size_t idx = ((size_t)((b*NN + i)*TT + t))*FF + o;
            out[idx]           = fmaxf(ax[r], 0.0f);
            out[OUT_OFF + idx] = fmaxf(au[r], 0.0f);
        }
    }
}

extern "C" void kernel_launch(void* const* d_in, const int* in_sizes, int n_in,
                              void* d_out, int out_size, void* d_ws, size_t ws_size,
                              hipStream_t stream) {
    const float* ori = (const float*)d_in[0];
    const float* unc = (const float*)d_in[1];
    const float* emb = (const float*)d_in[2];
    const float* W1  = (const float*)d_in[3];
    float* out = (float*)d_out;

    if (ws_size >= (size_t)WS_NEED) {
        char* ws = (char*)d_ws;
        unsigned short* xH = (unsigned short*)(ws);
        unsigned short* xL = (unsigned short*)(ws + (size_t)2*AE);
        unsigned short* xT = (unsigned short*)(ws + (size_t)4*AE);
        unsigned short* uT = (unsigned short*)(ws + (size_t)6*AE);
        unsigned short* eH = (unsigned short*)(ws + WS_EH);
        unsigned short* eL = (unsigned short*)(ws + WS_EL);
        unsigned short* wH = (unsigned short*)(ws + WS_WH);
        float* h2x  = (float*)(ws + WS_H2X);
        float* ne2  = (float*)(ws + WS_NE2);
        float* mArr = (float*)(ws + WS_M);

        prep_x<<<dim3(BB*TT*4), dim3(256), 0, stream>>>(ori, unc, xH, xL, xT, uT, h2x);
        prep_e<<<dim3(1),       dim3(256), 0, stream>>>(emb, W1, eH, eL, ne2, wH);
        prep_m<<<dim3(BB*TT),   dim3(256), 0, stream>>>(h2x, ne2, mArr);
        spag_main<<<dim3(BB*TT*8), dim3(256), 0, stream>>>(xH, xL, xT, uT, eH, eL, wH, mArr, out);
    } else {
        spag_fb<<<dim3(BB*TT*8), dim3(256), 0, stream>>>(ori, unc, emb, W1, out);
    }
}